// Round 12
// baseline (3655.998 us; speedup 1.0000x reference)
//
#include <hip/hip_runtime.h>
#include <stdint.h>

#define DEV static __device__ __forceinline__

typedef unsigned short u16;
typedef __attribute__((ext_vector_type(8))) short short8;
typedef __attribute__((ext_vector_type(4))) float f32x4;

#define B_     2
#define S_     2048
#define E_     768
#define H_     12
#define L_     2
#define HID_   3072
#define VOCAB_ 50257
#define VPAD_  50432
#define M_     4096
#define NQKV_  2304

DEV u16 f2bf(float f) {
  union { float f; unsigned u; } x; x.f = f;
  unsigned r = x.u + 0x7fffu + ((x.u >> 16) & 1u);
  return (u16)(r >> 16);
}

DEV void gload16(const void* g, void* lds) {
  __builtin_amdgcn_global_load_lds(
      (const __attribute__((address_space(1))) unsigned int*)g,
      (__attribute__((address_space(3))) unsigned int*)lds, 16, 0, 0);
}

// ---------------------------------------------------------------- transpose
__global__ __launch_bounds__(256) void k_transp(
    const float* __restrict__ in, u16* __restrict__ out,
    int R, int Cin, long long ib1, long long ib2, long long ob1, long long ob2, int zdiv)
{
  __shared__ float t[32][33];
  const int z = blockIdx.z;
  const float* ib = in  + (size_t)(z / zdiv) * ib1 + (size_t)(z % zdiv) * ib2;
  u16*         ob = out + (size_t)(z / zdiv) * ob1 + (size_t)(z % zdiv) * ob2;
  const int c0 = blockIdx.x * 32, r0 = blockIdx.y * 32;
  const int tx = threadIdx.x, ty = threadIdx.y;
#pragma unroll
  for (int i = 0; i < 4; i++) {
    const int c = c0 + tx, r = r0 + ty + i * 8;
    t[ty + i * 8][tx] = (c < Cin) ? ib[(size_t)r * Cin + c] : 0.f;
  }
  __syncthreads();
#pragma unroll
  for (int i = 0; i < 4; i++) {
    const int orow = c0 + ty + i * 8;
    ob[(size_t)orow * R + r0 + tx] = f2bf(t[tx][ty + i * 8]);
  }
}

__global__ __launch_bounds__(256) void k_pack_bias(
    const float* __restrict__ bq, const float* __restrict__ bk,
    const float* __restrict__ bv, float* __restrict__ bqkv)
{
  const int i = blockIdx.x * 256 + threadIdx.x;
  if (i >= L_ * NQKV_) return;
  const int l = i / NQKV_, n = i % NQKV_;
  const float* s = (n < 768) ? bq : (n < 1536) ? bk : bv;
  bqkv[i] = s[l * 768 + (n % 768)];
}

// ---------------------------------------------------------------- embed + PE
__global__ __launch_bounds__(256) void k_embed(
    const int* __restrict__ tok, const float* __restrict__ emb, float* __restrict__ x)
{
  const int idx = blockIdx.x * 256 + threadIdx.x;
  const int e = idx % E_;
  const int row = idx / E_;
  const int s = row & (S_ - 1);
  const int t = tok[row];
  const float ang = (float)s * expf((float)e * (-2.0f / 768.f) * 9.210340371976184f);
  const float pe = (e & 1) ? cosf(ang) : sinf(ang);
  x[idx] = emb[(size_t)t * E_ + e] + pe;
}

// ---------------------------------------------------------------- layernorm
__global__ __launch_bounds__(256) void k_ln(
    const float* __restrict__ xin, const float* __restrict__ sc,
    const float* __restrict__ bi, float* __restrict__ hout, u16* __restrict__ hb)
{
  const int row  = blockIdx.x * 4 + (threadIdx.x >> 6);
  const int lane = threadIdx.x & 63;
  const float* xr = xin + (size_t)row * E_;
  float v[12];
  float s = 0.f;
#pragma unroll
  for (int i = 0; i < 12; i++) { v[i] = xr[i * 64 + lane]; s += v[i]; }
#pragma unroll
  for (int o = 1; o < 64; o <<= 1) s += __shfl_xor(s, o);
  const float mu = s * (1.f / 768.f);
  float s2 = 0.f;
#pragma unroll
  for (int i = 0; i < 12; i++) { const float d = v[i] - mu; s2 += d * d; }
#pragma unroll
  for (int o = 1; o < 64; o <<= 1) s2 += __shfl_xor(s2, o);
  const float rs = rsqrtf(s2 * (1.f / 768.f) + 1e-5f);
#pragma unroll
  for (int i = 0; i < 12; i++) {
    const int c = i * 64 + lane;
    const float ov = (v[i] - mu) * rs * sc[c] + bi[c];
    hout[(size_t)row * E_ + c] = ov;
    hb[(size_t)row * E_ + c]   = f2bf(ov);
  }
}

// ---------------------------------------------------------------- GEMM (m97 128^2)
// EPI 0: +bias->bf16  1: relu(+bias)->bf16  2: +bias+res->f32  4: EPI2 + bf16 copy
template <int EPI>
__global__ __launch_bounds__(256) void k_gemm(
    const u16* __restrict__ A, const u16* __restrict__ Bt,
    const float* __restrict__ bias, const float* __restrict__ res,
    void* __restrict__ outp, u16* __restrict__ out2, int Mm, int Nn, int Kk)
{
  __shared__ __align__(16) u16 As[128 * 32];
  __shared__ __align__(16) u16 Bs[128 * 32];
  const int tid  = threadIdx.x;
  const int lane = tid & 63;
  const int wid  = tid >> 6;
  const int wr = wid >> 1, wc = wid & 1;
  const int m0 = blockIdx.y * 128, n0 = blockIdx.x * 128;

  const u16* Ab = A  + (size_t)m0 * Kk;
  const u16* Bb = Bt + (size_t)n0 * Kk;

  f32x4 acc[4][4];
#pragma unroll
  for (int i = 0; i < 4; i++)
#pragma unroll
    for (int j = 0; j < 4; j++) acc[i][j] = (f32x4){0.f, 0.f, 0.f, 0.f};

  const int c0 = tid, c1 = 256 + tid;
  const int a0row = c0 >> 2, a0k = (c0 & 3) * 8;
  const int a1row = c1 >> 2, a1k = (c1 & 3) * 8;
  const int nk = Kk >> 5;
  const int kg = (lane >> 4) * 8;
  const int arow = wr * 64 + (lane & 15);
  const int brow = wc * 64 + (lane & 15);

  for (int kt = 0; kt < nk; ++kt) {
    const int kof = kt * 32;
    __syncthreads();
    gload16(Ab + (size_t)a0row * Kk + kof + a0k, &As[c0 * 8]);
    gload16(Ab + (size_t)a1row * Kk + kof + a1k, &As[c1 * 8]);
    gload16(Bb + (size_t)a0row * Kk + kof + a0k, &Bs[c0 * 8]);
    gload16(Bb + (size_t)a1row * Kk + kof + a1k, &Bs[c1 * 8]);
    asm volatile("s_waitcnt vmcnt(0)" ::: "memory");
    __syncthreads();
    short8 af[4], bf[4];
#pragma unroll
    for (int i = 0; i < 4; i++) af[i] = *(const short8*)&As[(arow + i * 16) * 32 + kg];
#pragma unroll
    for (int i = 0; i < 4; i++) bf[i] = *(const short8*)&Bs[(brow + i * 16) * 32 + kg];
#pragma unroll
    for (int mi = 0; mi < 4; mi++)
#pragma unroll
      for (int ni = 0; ni < 4; ni++)
        acc[mi][ni] = __builtin_amdgcn_mfma_f32_16x16x32_bf16(af[mi], bf[ni], acc[mi][ni], 0, 0, 0);
  }

  const int colg = lane & 15;
  const int rowg = (lane >> 4) * 4;
#pragma unroll
  for (int mi = 0; mi < 4; mi++) {
#pragma unroll
    for (int ni = 0; ni < 4; ni++) {
      const int col = n0 + wc * 64 + ni * 16 + colg;
      const float bb = bias[col];
#pragma unroll
      for (int r = 0; r < 4; r++) {
        const int row = m0 + wr * 64 + mi * 16 + rowg + r;
        float v = acc[mi][ni][r] + bb;
        if (EPI == 0)      ((u16*)outp)[(size_t)row * Nn + col] = f2bf(v);
        else if (EPI == 1) ((u16*)outp)[(size_t)row * Nn + col] = f2bf(fmaxf(v, 0.f));
        else if (EPI == 2) ((float*)outp)[(size_t)row * Nn + col] = v + res[(size_t)row * Nn + col];
        else if (EPI == 4) {
          const float o = v + res[(size_t)row * Nn + col];
          ((float*)outp)[(size_t)row * Nn + col] = o;
          out2[(size_t)row * Nn + col] = f2bf(o);
        }
      }
    }
  }
}

// ---------------------------------------------------------------- GEMM 256^2 (vocab)
// SINGLE-buffer 64KB LDS -> 2 blocks/CU. Per K-tile: barrier, stage, vmcnt(0)
// + barrier, free-run compute. Co-resident block fills the stage/epilogue
// gaps (duty-cycle fix). R7-verified swizzle (0 conflicts), m-split decode.
__global__ __launch_bounds__(512, 4) void k_gemm256(
    const u16* __restrict__ A, const u16* __restrict__ Bt,
    const float* __restrict__ bias, float* __restrict__ out,
    int Nn, int Kk, int nreal, int mpx)
{
  __shared__ __align__(16) u16 As[256 * 64];
  __shared__ __align__(16) u16 Bs[256 * 64];

  const int id = blockIdx.x;
  const int xcd = id & 7;
  const int j = id >> 3;
  const int m0 = (xcd * mpx + (j % mpx)) * 256;
  const int n0 = (j / mpx) * 256;

  const int tid = threadIdx.x, lane = tid & 63, w = tid >> 6;
  const int wr = w >> 2, wcn = w & 3;
  const int l15 = lane & 15, ks = lane >> 4;

  const u16* Ab = A  + (size_t)m0 * Kk;
  const u16* Bb = Bt + (size_t)n0 * Kk;

  // wave w stages 8-row chunks {w, 8+w} of each 128-row half (linear LDS dest,
  // inverse-swizzled global source slot).
  const int srow  = lane >> 3;
  const int sslot = ((lane & 7) ^ srow) * 8;
  const int wrow  = w * 8;

  f32x4 acc[8][4];
#pragma unroll
  for (int i = 0; i < 8; i++)
#pragma unroll
    for (int n = 0; n < 4; n++) acc[i][n] = (f32x4){0.f, 0.f, 0.f, 0.f};

  const int nk = Kk >> 6;

  auto stage = [&](int ko) {  // 8 gloads per thread
    gload16(Ab + (size_t)(wrow + srow) * Kk + ko + sslot,       &As[wrow * 64]);
    gload16(Ab + (size_t)(64 + wrow + srow) * Kk + ko + sslot,  &As[(64 + wrow) * 64]);
    gload16(Ab + (size_t)(128 + wrow + srow) * Kk + ko + sslot, &As[(128 + wrow) * 64]);
    gload16(Ab + (size_t)(192 + wrow + srow) * Kk + ko + sslot, &As[(192 + wrow) * 64]);
    gload16(Bb + (size_t)(wrow + srow) * Kk + ko + sslot,       &Bs[wrow * 64]);
    gload16(Bb + (size_t)(64 + wrow + srow) * Kk + ko + sslot,  &Bs[(64 + wrow) * 64]);
    gload16(Bb + (size_t)(128 + wrow + srow) * Kk + ko + sslot, &Bs[(128 + wrow) * 64]);
    gload16(Bb + (size_t)(192 + wrow + srow) * Kk + ko + sslot, &Bs[(192 + wrow) * 64]);
  };

  short8 af[4], bf[4];
  auto ldA = [&](int fmh, int ksub) {
#pragma unroll
    for (int i = 0; i < 4; i++) {
      const int r = wr * 128 + fmh * 64 + i * 16 + l15;
      const int sl = ((ksub * 4 + ks) ^ (r & 7)) * 8;
      af[i] = *(const short8*)&As[r * 64 + sl];
    }
  };
  auto ldB = [&](int ksub) {
#pragma unroll
    for (int n = 0; n < 4; n++) {
      const int r = wcn * 64 + n * 16 + l15;
      const int sl = ((ksub * 4 + ks) ^ (r & 7)) * 8;
      bf[n] = *(const short8*)&Bs[r * 64 + sl];
    }
  };
  auto mm = [&](int fmh) {
    __builtin_amdgcn_s_setprio(1);
#pragma unroll
    for (int i = 0; i < 4; i++)
#pragma unroll
      for (int n = 0; n < 4; n++)
        acc[fmh * 4 + i][n] =
            __builtin_amdgcn_mfma_f32_16x16x32_bf16(af[i], bf[n], acc[fmh * 4 + i][n], 0, 0, 0);
    __builtin_amdgcn_s_setprio(0);
  };

  for (int t = 0; t < nk; ++t) {
    __builtin_amdgcn_s_barrier();            // all waves done reading prev tile
    stage(t << 6);
    asm volatile("s_waitcnt vmcnt(0)" ::: "memory");
    __builtin_amdgcn_sched_barrier(0);
    __builtin_amdgcn_s_barrier();
    __builtin_amdgcn_sched_barrier(0);
    // free-run compute (compiler lgkmcnt; co-resident block overlaps)
    ldA(0, 0); ldB(0); mm(0);
    ldA(1, 0); mm(1);
    ldA(0, 1); ldB(1); mm(0);
    ldA(1, 1); mm(1);
  }

  // epilogue: direct stores
#pragma unroll
  for (int fm = 0; fm < 8; fm++) {
    const int row = m0 + wr * 128 + fm * 16 + ks * 4;
#pragma unroll
    for (int n = 0; n < 4; n++) {
      const int col = n0 + wcn * 64 + n * 16 + l15;
      if (col < nreal) {
        const float bb = bias[col];
#pragma unroll
        for (int r = 0; r < 4; r++)
          out[(size_t)(row + r) * nreal + col] = acc[fm][n][r] + bb;
      }
    }
  }
}

// ---------------------------------------------------------------- attention
// QBLK=128 (8 waves x 16 q-rows), KVBLK=128, reversed launch order.
__global__ __launch_bounds__(512) void k_attn(
    const u16* __restrict__ qkv, const float* __restrict__ h, float* __restrict__ x)
{
  const int tid = threadIdx.x, lane = tid & 63, wid = tid >> 6;
  const int bh = blockIdx.y, b = bh / H_, hh = bh % H_;
  const int q0 = (gridDim.x - 1 - blockIdx.x) * 128;
  const int qw = q0 + wid * 16;

  __shared__ __align__(16) u16 Ks[128 * 72];
  __shared__ __align__(16) u16 Vt[64 * 136];
  __shared__ __align__(16) u16 Ps[8][16 * 136];

  const size_t rowbase = (size_t)b * S_;
  const u16* qb = qkv + rowbase * NQKV_ + hh * 64;
  const u16* kb = qb + 768;
  const u16* vb = qb + 1536;

  const int l15 = lane & 15;
  const int ks  = lane >> 4;
  const int kg  = ks * 8;
  const int ks4 = ks * 4;

  short8 qf0, qf1;
  {
    const u16* g = qb + (size_t)(qw + l15) * NQKV_ + kg;
    qf0 = *(const short8*)g;
    qf1 = *(const short8*)(g + 32);
  }

  f32x4 ov[4];
#pragma unroll
  for (int i = 0; i < 4; i++) ov[i] = (f32x4){0.f, 0.f, 0.f, 0.f};
  float mr[4], lr[4];
#pragma unroll
  for (int r = 0; r < 4; r++) { mr[r] = -1e30f; lr[r] = 0.f; }

  const int srow = tid >> 3;
  const int sc8  = (tid & 7) * 8;
  const int g8   = tid & 7;
  const int nkt  = (q0 >> 7) + 1;

  for (int kt = 0; kt < nkt; ++kt) {
    const int kbase = kt << 7;
    __syncthreads();
#pragma unroll
    for (int pass = 0; pass < 2; ++pass) {
      const int r = srow + pass * 64;
      const size_t gr = (size_t)(kbase + r) * NQKV_;
      const uint4 kd = *(const uint4*)(kb + gr + sc8);
      *(uint4*)&Ks[r * 72 + sc8] = kd;
      const uint4 vd = *(const uint4*)(vb + gr + sc8);
      const u16* ve = (const u16*)&vd;
      const int sb = (((r >> 3) ^ g8) << 3) + (r & 7);
#pragma unroll
      for (int jj = 0; jj < 8; jj++) Vt[(sc8 + jj) * 136 + sb] = ve[jj];
    }
    __syncthreads();

    const bool last = (kt == nkt - 1);
    float p[8][4], mt[4];
#pragma unroll
    for (int r = 0; r < 4; r++) mt[r] = -1e30f;
#pragma unroll
    for (int ct = 0; ct < 8; ++ct) {
      f32x4 s = (f32x4){0.f, 0.f, 0.f, 0.f};
      const short8 kf0 = *(const short8*)&Ks[(ct * 16 + l15) * 72 + kg];
      const short8 kf1 = *(const short8*)&Ks[(ct * 16 + l15) * 72 + 32 + kg];
      s = __builtin_amdgcn_mfma_f32_16x16x32_bf16(qf0, kf0, s, 0, 0, 0);
      s = __builtin_amdgcn_mfma_f32_16x16x32_bf16(qf1, kf1, s, 0, 0, 0);
      const int kc = kbase + ct * 16 + l15;
#pragma unroll
      for (int r = 0; r < 4; r++) {
        float v = s[r] * 0.125f;
        if (last && kc > qw + ks4 + r) v = -1e30f;
        p[ct][r] = v;
        mt[r] = fmaxf(mt[r], v);
      }
    }
#pragma unroll
    for (int r = 0; r < 4; r++) {
#pragma unroll
      for (int off = 1; off < 16; off <<= 1) mt[r] = fmaxf(mt[r], __shfl_xor(mt[r], off));
    }
    float al[4], ps[4];
#pragma unroll
    for (int r = 0; r < 4; r++) {
      const float mn = fmaxf(mr[r], mt[r]);
      al[r] = __expf(mr[r] - mn);
      mr[r] = mn;
      ps[r] = 0.f;
    }
#pragma unroll
    for (int ct = 0; ct < 8; ++ct)
#pragma unroll
      for (int r = 0; r < 4; r++) {
        p[ct][r] = __expf(p[ct][r] - mr[r]);
        ps[r] += p[ct][r];
      }
#pragma unroll
    for (int r = 0; r < 4; r++) {
#pragma unroll
      for (int off = 1; off < 16; off <<= 1) ps[r] += __shfl_xor(ps[r], off);
      lr[r] = lr[r] * al[r] + ps[r];
    }
#pragma unroll
    for (int dt = 0; dt < 4; dt++)
#pragma unroll
      for (int r = 0; r < 4; r++) ov[dt][r] *= al[r];

    u16* pw = &Ps[wid][0];
#pragma unroll
    for (int ct = 0; ct < 8; ++ct)
#pragma unroll
      for (int r = 0; r < 4; r++)
        pw[(ks4 + r) * 136 + ct * 16 + l15] = f2bf(p[ct][r]);
#pragma unroll
    for (int c = 0; c < 4; ++c) {
      const short8 pa = *(const short8*)&pw[l15 * 136 + c * 32 + kg];
#pragma unroll
      for (int dt = 0; dt < 4; dt++) {
        const int d = dt * 16 + l15;
        const int sb = (((c * 4 + ks) ^ ((d >> 3) & 7)) << 3);
        const short8 vf = *(const short8*)&Vt[d * 136 + sb];
        ov[dt] = __builtin_amdgcn_mfma_f32_16x16x32_bf16(pa, vf, ov[dt], 0, 0, 0);
      }
    }
  }

#pragma unroll
  for (int dt = 0; dt < 4; dt++) {
#pragma unroll
    for (int r = 0; r < 4; r++) {
      const int qr = qw + ks4 + r;
      const int col = hh * 64 + dt * 16 + l15;
      const size_t idx = (rowbase + qr) * (size_t)E_ + col;
      x[idx] = h[idx] + ov[dt][r] / lr[r];
    }
  }
}

// ---------------------------------------------------------------- launch
extern "C" void kernel_launch(void* const* d_in, const int* in_sizes, int n_in,
                              void* d_out, int out_size, void* d_ws, size_t ws_size,
                              hipStream_t stream)
{
  const int*   tok  = (const int*)  d_in[0];
  const float* emb  = (const float*)d_in[1];
  const float* ln1s = (const float*)d_in[2];
  const float* ln1b = (const float*)d_in[3];
  const float* Wq   = (const float*)d_in[4];
  const float* bq   = (const float*)d_in[5];
  const float* Wk   = (const float*)d_in[6];
  const float* bk   = (const float*)d_in[7];
  const float* Wv   = (const float*)d_in[8];
  const float* bv   = (const float*)d_in[9];
  const float* ln2s = (const float*)d_in[10];
  const float* ln2b = (const float*)d_in[11];
  const float* W1   = (const float*)d_in[12];
  const float* b1   = (const float*)d_in[13];
  const float* W2   = (const float*)d_in[14];
  const float* b2   = (const float*)d_in[15];
  const float* Wo   = (const float*)d_in[16];
  const float* bo   = (const float*)d_in[17];
  float* out = (float*)d_out;

  char* p = (char*)d_ws;
  float* xf    = (float*)p; p += (size_t)M_ * E_ * 4;
  float* hf    = (float*)p; p += (size_t)M_ * E_ * 4;
  u16*   hb    = (u16*)p;   p += (size_t)M_ * E_ * 2;
  u16*   xb    = (u16*)p;   p += (size_t)M_ * E_ * 2;
  u16*   midb  = (u16*)p;   p += (size_t)M_ * HID_ * 2;
  u16*   qkvb  = (u16*)p;   p += (size_t)M_ * NQKV_ * 2;
  u16*   Wqkvt = (u16*)p;   p += (size_t)L_ * NQKV_ * E_ * 2;
  u16*   W1t   = (u16*)p;   p += (size_t)L_ * HID_ * E_ * 2;
  u16*   W2t   = (u16*)p;   p += (size_t)L_ * E_ * HID_ * 2;
  u16*   Wot   = (u16*)p;   p += (size_t)VPAD_ * E_ * 2;
  float* bqkv  = (float*)p; p += (size_t)L_ * NQKV_ * 4;

  const dim3 tb32(32, 8, 1);
  k_transp<<<dim3(HID_ / 32, E_ / 32, L_), tb32, 0, stream>>>(
      W1, W1t, E_, HID_, (long long)E_ * HID_, 0, (long long)HID_ * E_, 0, 1);
  k_transp<<<dim3(E_ / 32, HID_ / 32, L_), tb32, 0, stream>>>(
      W2, W2t, HID_, E_, (long long)HID_ * E_, 0, (long long)E_ * HID_, 0, 1);
  k_transp<<<dim3(VPAD_ / 32, E_ / 32, 1), tb32, 0, stream>>>(
      Wo, Wot, E_, VOCAB_, 0, 0, 0, 0, 1);
  k_transp<<<dim3(2, E_ / 32, L_ * H_), tb32, 0, stream>>>(
      Wq, Wqkvt, E_, 64, (long long)H_ * E_ * 64, (long long)E_ * 64,
      (long long)NQKV_ * E_, 64LL * E_, H_);
  k_transp<<<dim3(2, E_ / 32, L_ * H_), tb32, 0, stream>>>(
      Wk, Wqkvt + 768 * E_, E_, 64, (long long)H_ * E_ * 64, (long long)E_ * 64,
      (long long)NQKV_ * E_, 64LL * E_, H_);
  k_transp<<<dim3(2, E_ / 32, L_ * H_), tb32, 0, stream>>>(
      Wv, Wqkvt + 1536 * E_, E_, 64, (long long)H_ * E_ * 64, (long long)E_ * 64,
      (long long)NQKV_ * E_, 64LL * E_, H_);
  k_pack_bias<<<18, 256, 0, stream>>>(bq, bk, bv, bqkv);
  k_embed<<<(M_ * E_) / 256, 256, 0, stream>>>(tok, emb, xf);

  for (int l = 0; l < L_; ++l) {
    k_ln<<<M_ / 4, 256, 0, stream>>>(xf, ln1s + l * E_, ln1b + l * E_, hf, hb);
    k_gemm<0><<<dim3(NQKV_ / 128, M_ / 128), 256, 0, stream>>>(
        hb, Wqkvt + (size_t)l * NQKV_ * E_, bqkv + l * NQKV_, nullptr, qkvb, nullptr,
        M_, NQKV_, E_);
    k_attn<<<dim3(S_ / 128, B_ * H_), 512, 0, stream>>>(qkvb, hf, xf);
    k_ln<<<M_ / 4, 256, 0, stream>>>(xf, ln2s + l * E_, ln2b + l * E_, hf, hb);
    k_gemm<1><<<dim3(HID_ / 128, M_ / 128), 256, 0, stream>>>(
        hb, W1t + (size_t)l * HID_ * E_, b1 + l * HID_, nullptr, midb, nullptr,
        M_, HID_, E_);
    if (l == L_ - 1) {
      k_gemm<4><<<dim3(E_ / 128, M_ / 128), 256, 0, stream>>>(
          midb, W2t + (size_t)l * E_ * HID_, b2 + l * E_, hf, xf, xb, M_, E_, HID_);
    } else {
      k_gemm<2><<<dim3(E_ / 128, M_ / 128), 256, 0, stream>>>(
          midb, W2t + (size_t)l * E_ * HID_, b2 + l * E_, hf, xf, nullptr, M_, E_, HID_);
    }
  }
  k_gemm256<<<dim3(8 * 2 * (VPAD_ / 256)), 512, 0, stream>>>(
      xb, Wot, bo, out, VPAD_, E_, VOCAB_, 2);
}

// Round 13
// 1185.605 us; speedup vs baseline: 3.0837x; 3.0837x over previous
//
#include <hip/hip_runtime.h>
#include <stdint.h>

#define DEV static __device__ __forceinline__

typedef unsigned short u16;
typedef __attribute__((ext_vector_type(8))) short short8;
typedef __attribute__((ext_vector_type(4))) float f32x4;

#define B_     2
#define S_     2048
#define E_     768
#define H_     12
#define L_     2
#define HID_   3072
#define VOCAB_ 50257
#define VPAD_  50432
#define M_     4096
#define NQKV_  2304

DEV u16 f2bf(float f) {
  union { float f; unsigned u; } x; x.f = f;
  unsigned r = x.u + 0x7fffu + ((x.u >> 16) & 1u);
  return (u16)(r >> 16);
}

DEV void gload16(const void* g, void* lds) {
  __builtin_amdgcn_global_load_lds(
      (const __attribute__((address_space(1))) unsigned int*)g,
      (__attribute__((address_space(3))) unsigned int*)lds, 16, 0, 0);
}

// ---------------------------------------------------------------- transpose
__global__ __launch_bounds__(256) void k_transp(
    const float* __restrict__ in, u16* __restrict__ out,
    int R, int Cin, long long ib1, long long ib2, long long ob1, long long ob2, int zdiv)
{
  __shared__ float t[32][33];
  const int z = blockIdx.z;
  const float* ib = in  + (size_t)(z / zdiv) * ib1 + (size_t)(z % zdiv) * ib2;
  u16*         ob = out + (size_t)(z / zdiv) * ob1 + (size_t)(z % zdiv) * ob2;
  const int c0 = blockIdx.x * 32, r0 = blockIdx.y * 32;
  const int tx = threadIdx.x, ty = threadIdx.y;
#pragma unroll
  for (int i = 0; i < 4; i++) {
    const int c = c0 + tx, r = r0 + ty + i * 8;
    t[ty + i * 8][tx] = (c < Cin) ? ib[(size_t)r * Cin + c] : 0.f;
  }
  __syncthreads();
#pragma unroll
  for (int i = 0; i < 4; i++) {
    const int orow = c0 + ty + i * 8;
    ob[(size_t)orow * R + r0 + tx] = f2bf(t[tx][ty + i * 8]);
  }
}

__global__ __launch_bounds__(256) void k_pack_bias(
    const float* __restrict__ bq, const float* __restrict__ bk,
    const float* __restrict__ bv, float* __restrict__ bqkv)
{
  const int i = blockIdx.x * 256 + threadIdx.x;
  if (i >= L_ * NQKV_) return;
  const int l = i / NQKV_, n = i % NQKV_;
  const float* s = (n < 768) ? bq : (n < 1536) ? bk : bv;
  bqkv[i] = s[l * 768 + (n % 768)];
}

// ---------------------------------------------------------------- embed + PE
__global__ __launch_bounds__(256) void k_embed(
    const int* __restrict__ tok, const float* __restrict__ emb, float* __restrict__ x)
{
  const int idx = blockIdx.x * 256 + threadIdx.x;
  const int e = idx % E_;
  const int row = idx / E_;
  const int s = row & (S_ - 1);
  const int t = tok[row];
  const float ang = (float)s * expf((float)e * (-2.0f / 768.f) * 9.210340371976184f);
  const float pe = (e & 1) ? cosf(ang) : sinf(ang);
  x[idx] = emb[(size_t)t * E_ + e] + pe;
}

// ---------------------------------------------------------------- layernorm
__global__ __launch_bounds__(256) void k_ln(
    const float* __restrict__ xin, const float* __restrict__ sc,
    const float* __restrict__ bi, float* __restrict__ hout, u16* __restrict__ hb)
{
  const int row  = blockIdx.x * 4 + (threadIdx.x >> 6);
  const int lane = threadIdx.x & 63;
  const float* xr = xin + (size_t)row * E_;
  float v[12];
  float s = 0.f;
#pragma unroll
  for (int i = 0; i < 12; i++) { v[i] = xr[i * 64 + lane]; s += v[i]; }
#pragma unroll
  for (int o = 1; o < 64; o <<= 1) s += __shfl_xor(s, o);
  const float mu = s * (1.f / 768.f);
  float s2 = 0.f;
#pragma unroll
  for (int i = 0; i < 12; i++) { const float d = v[i] - mu; s2 += d * d; }
#pragma unroll
  for (int o = 1; o < 64; o <<= 1) s2 += __shfl_xor(s2, o);
  const float rs = rsqrtf(s2 * (1.f / 768.f) + 1e-5f);
#pragma unroll
  for (int i = 0; i < 12; i++) {
    const int c = i * 64 + lane;
    const float ov = (v[i] - mu) * rs * sc[c] + bi[c];
    hout[(size_t)row * E_ + c] = ov;
    hb[(size_t)row * E_ + c]   = f2bf(ov);
  }
}

// ---------------------------------------------------------------- GEMM (m97 128^2)
// EPI 0: +bias->bf16  1: relu(+bias)->bf16  2: +bias+res->f32  4: EPI2 + bf16 copy
template <int EPI>
__global__ __launch_bounds__(256) void k_gemm(
    const u16* __restrict__ A, const u16* __restrict__ Bt,
    const float* __restrict__ bias, const float* __restrict__ res,
    void* __restrict__ outp, u16* __restrict__ out2, int Mm, int Nn, int Kk)
{
  __shared__ __align__(16) u16 As[128 * 32];
  __shared__ __align__(16) u16 Bs[128 * 32];
  const int tid  = threadIdx.x;
  const int lane = tid & 63;
  const int wid  = tid >> 6;
  const int wr = wid >> 1, wc = wid & 1;
  const int m0 = blockIdx.y * 128, n0 = blockIdx.x * 128;

  const u16* Ab = A  + (size_t)m0 * Kk;
  const u16* Bb = Bt + (size_t)n0 * Kk;

  f32x4 acc[4][4];
#pragma unroll
  for (int i = 0; i < 4; i++)
#pragma unroll
    for (int j = 0; j < 4; j++) acc[i][j] = (f32x4){0.f, 0.f, 0.f, 0.f};

  const int c0 = tid, c1 = 256 + tid;
  const int a0row = c0 >> 2, a0k = (c0 & 3) * 8;
  const int a1row = c1 >> 2, a1k = (c1 & 3) * 8;
  const int nk = Kk >> 5;
  const int kg = (lane >> 4) * 8;
  const int arow = wr * 64 + (lane & 15);
  const int brow = wc * 64 + (lane & 15);

  for (int kt = 0; kt < nk; ++kt) {
    const int kof = kt * 32;
    __syncthreads();
    gload16(Ab + (size_t)a0row * Kk + kof + a0k, &As[c0 * 8]);
    gload16(Ab + (size_t)a1row * Kk + kof + a1k, &As[c1 * 8]);
    gload16(Bb + (size_t)a0row * Kk + kof + a0k, &Bs[c0 * 8]);
    gload16(Bb + (size_t)a1row * Kk + kof + a1k, &Bs[c1 * 8]);
    asm volatile("s_waitcnt vmcnt(0)" ::: "memory");
    __syncthreads();
    short8 af[4], bf[4];
#pragma unroll
    for (int i = 0; i < 4; i++) af[i] = *(const short8*)&As[(arow + i * 16) * 32 + kg];
#pragma unroll
    for (int i = 0; i < 4; i++) bf[i] = *(const short8*)&Bs[(brow + i * 16) * 32 + kg];
#pragma unroll
    for (int mi = 0; mi < 4; mi++)
#pragma unroll
      for (int ni = 0; ni < 4; ni++)
        acc[mi][ni] = __builtin_amdgcn_mfma_f32_16x16x32_bf16(af[mi], bf[ni], acc[mi][ni], 0, 0, 0);
  }

  const int colg = lane & 15;
  const int rowg = (lane >> 4) * 4;
#pragma unroll
  for (int mi = 0; mi < 4; mi++) {
#pragma unroll
    for (int ni = 0; ni < 4; ni++) {
      const int col = n0 + wc * 64 + ni * 16 + colg;
      const float bb = bias[col];
#pragma unroll
      for (int r = 0; r < 4; r++) {
        const int row = m0 + wr * 64 + mi * 16 + rowg + r;
        float v = acc[mi][ni][r] + bb;
        if (EPI == 0)      ((u16*)outp)[(size_t)row * Nn + col] = f2bf(v);
        else if (EPI == 1) ((u16*)outp)[(size_t)row * Nn + col] = f2bf(fmaxf(v, 0.f));
        else if (EPI == 2) ((float*)outp)[(size_t)row * Nn + col] = v + res[(size_t)row * Nn + col];
        else if (EPI == 4) {
          const float o = v + res[(size_t)row * Nn + col];
          ((float*)outp)[(size_t)row * Nn + col] = o;
          out2[(size_t)row * Nn + col] = f2bf(o);
        }
      }
    }
  }
}

// ---------------------------------------------------------------- GEMM 256^2 (vocab) — R7 best (566us)
__global__ __launch_bounds__(512, 2) void k_gemm256(
    const u16* __restrict__ A, const u16* __restrict__ Bt,
    const float* __restrict__ bias, float* __restrict__ out,
    int Nn, int Kk, int nreal, int mpx)
{
  __shared__ __align__(16) u16 As[2][256 * 64];
  __shared__ __align__(16) u16 Bs[2][256 * 64];

  const int id = blockIdx.x;
  const int xcd = id & 7;
  const int j = id >> 3;
  const int m0 = (xcd * mpx + (j % mpx)) * 256;
  const int n0 = (j / mpx) * 256;

  const int tid = threadIdx.x, lane = tid & 63, w = tid >> 6;
  const int wr = w >> 2, wcn = w & 3;
  const int l15 = lane & 15, ks = lane >> 4;

  const u16* Ab = A  + (size_t)m0 * Kk;
  const u16* Bb = Bt + (size_t)n0 * Kk;

  const int srow  = lane >> 3;
  const int sslot = ((lane & 7) ^ srow) * 8;
  const int wrow  = w * 8;

  f32x4 acc[8][4];
#pragma unroll
  for (int i = 0; i < 8; i++)
#pragma unroll
    for (int n = 0; n < 4; n++) acc[i][n] = (f32x4){0.f, 0.f, 0.f, 0.f};

  const int nk = Kk >> 6;

  auto stage = [&](int b, int ko) {
    gload16(Ab + (size_t)(wrow + srow) * Kk + ko + sslot,       &As[b][wrow * 64]);
    gload16(Ab + (size_t)(64 + wrow + srow) * Kk + ko + sslot,  &As[b][(64 + wrow) * 64]);
    gload16(Ab + (size_t)(128 + wrow + srow) * Kk + ko + sslot, &As[b][(128 + wrow) * 64]);
    gload16(Ab + (size_t)(192 + wrow + srow) * Kk + ko + sslot, &As[b][(192 + wrow) * 64]);
    gload16(Bb + (size_t)(wrow + srow) * Kk + ko + sslot,       &Bs[b][wrow * 64]);
    gload16(Bb + (size_t)(64 + wrow + srow) * Kk + ko + sslot,  &Bs[b][(64 + wrow) * 64]);
    gload16(Bb + (size_t)(128 + wrow + srow) * Kk + ko + sslot, &Bs[b][(128 + wrow) * 64]);
    gload16(Bb + (size_t)(192 + wrow + srow) * Kk + ko + sslot, &Bs[b][(192 + wrow) * 64]);
  };

  short8 af[4], bf[4];
  auto ldA = [&](int b, int fmh, int ksub) {
#pragma unroll
    for (int i = 0; i < 4; i++) {
      const int r = wr * 128 + fmh * 64 + i * 16 + l15;
      const int sl = ((ksub * 4 + ks) ^ (r & 7)) * 8;
      af[i] = *(const short8*)&As[b][r * 64 + sl];
    }
  };
  auto ldB = [&](int b, int ksub) {
#pragma unroll
    for (int n = 0; n < 4; n++) {
      const int r = wcn * 64 + n * 16 + l15;
      const int sl = ((ksub * 4 + ks) ^ (r & 7)) * 8;
      bf[n] = *(const short8*)&Bs[b][r * 64 + sl];
    }
  };
  auto mm = [&](int fmh) {
    __builtin_amdgcn_s_setprio(1);
#pragma unroll
    for (int i = 0; i < 4; i++)
#pragma unroll
      for (int n = 0; n < 4; n++)
        acc[fmh * 4 + i][n] =
            __builtin_amdgcn_mfma_f32_16x16x32_bf16(af[i], bf[n], acc[fmh * 4 + i][n], 0, 0, 0);
    __builtin_amdgcn_s_setprio(0);
  };

  stage(0, 0);
  if (nk > 1) {
    stage(1, 64);
    asm volatile("s_waitcnt vmcnt(8)" ::: "memory");
  } else {
    asm volatile("s_waitcnt vmcnt(0)" ::: "memory");
  }
  __builtin_amdgcn_s_barrier();

  for (int t = 0; t < nk; ++t) {
    const int cur = t & 1;
    ldA(cur, 0, 0); ldB(cur, 0); mm(0);
    ldA(cur, 1, 0); mm(1);
    ldA(cur, 0, 1); ldB(cur, 1); mm(0);
    ldA(cur, 1, 1); mm(1);
    __builtin_amdgcn_sched_barrier(0);
    __builtin_amdgcn_s_barrier();
    __builtin_amdgcn_sched_barrier(0);
    if (t + 2 < nk) {
      stage(cur, (t + 2) << 6);
      asm volatile("s_waitcnt vmcnt(8)" ::: "memory");
    } else if (t + 1 < nk) {
      asm volatile("s_waitcnt vmcnt(0)" ::: "memory");
    }
    __builtin_amdgcn_sched_barrier(0);
    __builtin_amdgcn_s_barrier();
    __builtin_amdgcn_sched_barrier(0);
  }

#pragma unroll
  for (int fm = 0; fm < 8; fm++) {
    const int row = m0 + wr * 128 + fm * 16 + ks * 4;
#pragma unroll
    for (int n = 0; n < 4; n++) {
      const int col = n0 + wcn * 64 + n * 16 + l15;
      if (col < nreal) {
        const float bb = bias[col];
#pragma unroll
        for (int r = 0; r < 4; r++)
          out[(size_t)(row + r) * nreal + col] = acc[fm][n][r] + bb;
      }
    }
  }
}

// ---------------------------------------------------------------- attention
// QBLK=128 (8 waves x 16 q-rows), KVBLK=128, reversed launch order.
__global__ __launch_bounds__(512) void k_attn(
    const u16* __restrict__ qkv, const float* __restrict__ h, float* __restrict__ x)
{
  const int tid = threadIdx.x, lane = tid & 63, wid = tid >> 6;
  const int bh = blockIdx.y, b = bh / H_, hh = bh % H_;
  const int q0 = (gridDim.x - 1 - blockIdx.x) * 128;
  const int qw = q0 + wid * 16;

  __shared__ __align__(16) u16 Ks[128 * 72];
  __shared__ __align__(16) u16 Vt[64 * 136];
  __shared__ __align__(16) u16 Ps[8][16 * 136];

  const size_t rowbase = (size_t)b * S_;
  const u16* qb = qkv + rowbase * NQKV_ + hh * 64;
  const u16* kb = qb + 768;
  const u16* vb = qb + 1536;

  const int l15 = lane & 15;
  const int ks  = lane >> 4;
  const int kg  = ks * 8;
  const int ks4 = ks * 4;

  short8 qf0, qf1;
  {
    const u16* g = qb + (size_t)(qw + l15) * NQKV_ + kg;
    qf0 = *(const short8*)g;
    qf1 = *(const short8*)(g + 32);
  }

  f32x4 ov[4];
#pragma unroll
  for (int i = 0; i < 4; i++) ov[i] = (f32x4){0.f, 0.f, 0.f, 0.f};
  float mr[4], lr[4];
#pragma unroll
  for (int r = 0; r < 4; r++) { mr[r] = -1e30f; lr[r] = 0.f; }

  const int srow = tid >> 3;
  const int sc8  = (tid & 7) * 8;
  const int g8   = tid & 7;
  const int nkt  = (q0 >> 7) + 1;

  for (int kt = 0; kt < nkt; ++kt) {
    const int kbase = kt << 7;
    __syncthreads();
#pragma unroll
    for (int pass = 0; pass < 2; ++pass) {
      const int r = srow + pass * 64;
      const size_t gr = (size_t)(kbase + r) * NQKV_;
      const uint4 kd = *(const uint4*)(kb + gr + sc8);
      *(uint4*)&Ks[r * 72 + sc8] = kd;
      const uint4 vd = *(const uint4*)(vb + gr + sc8);
      const u16* ve = (const u16*)&vd;
      const int sb = (((r >> 3) ^ g8) << 3) + (r & 7);
#pragma unroll
      for (int jj = 0; jj < 8; jj++) Vt[(sc8 + jj) * 136 + sb] = ve[jj];
    }
    __syncthreads();

    const bool last = (kt == nkt - 1);
    float p[8][4], mt[4];
#pragma unroll
    for (int r = 0; r < 4; r++) mt[r] = -1e30f;
#pragma unroll
    for (int ct = 0; ct < 8; ++ct) {
      f32x4 s = (f32x4){0.f, 0.f, 0.f, 0.f};
      const short8 kf0 = *(const short8*)&Ks[(ct * 16 + l15) * 72 + kg];
      const short8 kf1 = *(const short8*)&Ks[(ct * 16 + l15) * 72 + 32 + kg];
      s = __builtin_amdgcn_mfma_f32_16x16x32_bf16(qf0, kf0, s, 0, 0, 0);
      s = __builtin_amdgcn_mfma_f32_16x16x32_bf16(qf1, kf1, s, 0, 0, 0);
      const int kc = kbase + ct * 16 + l15;
#pragma unroll
      for (int r = 0; r < 4; r++) {
        float v = s[r] * 0.125f;
        if (last && kc > qw + ks4 + r) v = -1e30f;
        p[ct][r] = v;
        mt[r] = fmaxf(mt[r], v);
      }
    }
#pragma unroll
    for (int r = 0; r < 4; r++) {
#pragma unroll
      for (int off = 1; off < 16; off <<= 1) mt[r] = fmaxf(mt[r], __shfl_xor(mt[r], off));
    }
    float al[4], ps[4];
#pragma unroll
    for (int r = 0; r < 4; r++) {
      const float mn = fmaxf(mr[r], mt[r]);
      al[r] = __expf(mr[r] - mn);
      mr[r] = mn;
      ps[r] = 0.f;
    }
#pragma unroll
    for (int ct = 0; ct < 8; ++ct)
#pragma unroll
      for (int r = 0; r < 4; r++) {
        p[ct][r] = __expf(p[ct][r] - mr[r]);
        ps[r] += p[ct][r];
      }
#pragma unroll
    for (int r = 0; r < 4; r++) {
#pragma unroll
      for (int off = 1; off < 16; off <<= 1) ps[r] += __shfl_xor(ps[r], off);
      lr[r] = lr[r] * al[r] + ps[r];
    }
#pragma unroll
    for (int dt = 0; dt < 4; dt++)
#pragma unroll
      for (int r = 0; r < 4; r++) ov[dt][r] *= al[r];

    u16* pw = &Ps[wid][0];
#pragma unroll
    for (int ct = 0; ct < 8; ++ct)
#pragma unroll
      for (int r = 0; r < 4; r++)
        pw[(ks4 + r) * 136 + ct * 16 + l15] = f2bf(p[ct][r]);
#pragma unroll
    for (int c = 0; c < 4; ++c) {
      const short8 pa = *(const short8*)&pw[l15 * 136 + c * 32 + kg];
#pragma unroll
      for (int dt = 0; dt < 4; dt++) {
        const int d = dt * 16 + l15;
        const int sb = (((c * 4 + ks) ^ ((d >> 3) & 7)) << 3);
        const short8 vf = *(const short8*)&Vt[d * 136 + sb];
        ov[dt] = __builtin_amdgcn_mfma_f32_16x16x32_bf16(pa, vf, ov[dt], 0, 0, 0);
      }
    }
  }

#pragma unroll
  for (int dt = 0; dt < 4; dt++) {
#pragma unroll
    for (int r = 0; r < 4; r++) {
      const int qr = qw + ks4 + r;
      const int col = hh * 64 + dt * 16 + l15;
      const size_t idx = (rowbase + qr) * (size_t)E_ + col;
      x[idx] = h[idx] + ov[dt][r] / lr[r];
    }
  }
}

// ---------------------------------------------------------------- launch
extern "C" void kernel_launch(void* const* d_in, const int* in_sizes, int n_in,
                              void* d_out, int out_size, void* d_ws, size_t ws_size,
                              hipStream_t stream)
{
  const int*   tok  = (const int*)  d_in[0];
  const float* emb  = (const float*)d_in[1];
  const float* ln1s = (const float*)d_in[2];
  const float* ln1b = (const float*)d_in[3];
  const float* Wq   = (const float*)d_in[4];
  const float* bq   = (const float*)d_in[5];
  const float* Wk   = (const float*)d_in[6];
  const float* bk   = (const float*)d_in[7];
  const float* Wv   = (const float*)d_in[8];
  const float* bv   = (const float*)d_in[9];
  const float* ln2s = (const float*)d_in[10];
  const float* ln2b = (const float*)d_in[11];
  const float* W1   = (const float*)d_in[12];
  const float* b1   = (const float*)d_in[13];
  const float* W2   = (const float*)d_in[14];
  const float* b2   = (const float*)d_in[15];
  const float* Wo   = (const float*)d_in[16];
  const float* bo   = (const float*)d_in[17];
  float* out = (float*)d_out;

  char* p = (char*)d_ws;
  float* xf    = (float*)p; p += (size_t)M_ * E_ * 4;
  float* hf    = (float*)p; p += (size_t)M_ * E_ * 4;
  u16*   hb    = (u16*)p;   p += (size_t)M_ * E_ * 2;
  u16*   xb    = (u16*)p;   p += (size_t)M_ * E_ * 2;
  u16*   midb  = (u16*)p;   p += (size_t)M_ * HID_ * 2;
  u16*   qkvb  = (u16*)p;   p += (size_t)M_ * NQKV_ * 2;
  u16*   Wqkvt = (u16*)p;   p += (size_t)L_ * NQKV_ * E_ * 2;
  u16*   W1t   = (u16*)p;   p += (size_t)L_ * HID_ * E_ * 2;
  u16*   W2t   = (u16*)p;   p += (size_t)L_ * E_ * HID_ * 2;
  u16*   Wot   = (u16*)p;   p += (size_t)VPAD_ * E_ * 2;
  float* bqkv  = (float*)p; p += (size_t)L_ * NQKV_ * 4;

  const dim3 tb32(32, 8, 1);
  k_transp<<<dim3(HID_ / 32, E_ / 32, L_), tb32, 0, stream>>>(
      W1, W1t, E_, HID_, (long long)E_ * HID_, 0, (long long)HID_ * E_, 0, 1);
  k_transp<<<dim3(E_ / 32, HID_ / 32, L_), tb32, 0, stream>>>(
      W2, W2t, HID_, E_, (long long)HID_ * E_, 0, (long long)E_ * HID_, 0, 1);
  k_transp<<<dim3(VPAD_ / 32, E_ / 32, 1), tb32, 0, stream>>>(
      Wo, Wot, E_, VOCAB_, 0, 0, 0, 0, 1);
  k_transp<<<dim3(2, E_ / 32, L_ * H_), tb32, 0, stream>>>(
      Wq, Wqkvt, E_, 64, (long long)H_ * E_ * 64, (long long)E_ * 64,
      (long long)NQKV_ * E_, 64LL * E_, H_);
  k_transp<<<dim3(2, E_ / 32, L_ * H_), tb32, 0, stream>>>(
      Wk, Wqkvt + 768 * E_, E_, 64, (long long)H_ * E_ * 64, (long long)E_ * 64,
      (long long)NQKV_ * E_, 64LL * E_, H_);
  k_transp<<<dim3(2, E_ / 32, L_ * H_), tb32, 0, stream>>>(
      Wv, Wqkvt + 1536 * E_, E_, 64, (long long)H_ * E_ * 64, (long long)E_ * 64,
      (long long)NQKV_ * E_, 64LL * E_, H_);
  k_pack_bias<<<18, 256, 0, stream>>>(bq, bk, bv, bqkv);
  k_embed<<<(M_ * E_) / 256, 256, 0, stream>>>(tok, emb, xf);

  for (int l = 0; l < L_; ++l) {
    k_ln<<<M_ / 4, 256, 0, stream>>>(xf, ln1s + l * E_, ln1b + l * E_, hf, hb);
    k_gemm<0><<<dim3(NQKV_ / 128, M_ / 128), 256, 0, stream>>>(
        hb, Wqkvt + (size_t)l * NQKV_ * E_, bqkv + l * NQKV_, nullptr, qkvb, nullptr,
        M_, NQKV_, E_);
    k_attn<<<dim3(S_ / 128, B_ * H_), 512, 0, stream>>>(qkvb, hf, xf);
    k_ln<<<M_ / 4, 256, 0, stream>>>(xf, ln2s + l * E_, ln2b + l * E_, hf, hb);
    k_gemm<1><<<dim3(HID_ / 128, M_ / 128), 256, 0, stream>>>(
        hb, W1t + (size_t)l * HID_ * E_, b1 + l * HID_, nullptr, midb, nullptr,
        M_, HID_, E_);
    if (l == L_ - 1) {
      k_gemm<4><<<dim3(E_ / 128, M_ / 128), 256, 0, stream>>>(
          midb, W2t + (size_t)l * E_ * HID_, b2 + l * E_, hf, xf, xb, M_, E_, HID_);
    } else {
      k_gemm<2><<<dim3(E_ / 128, M_ / 128), 256, 0, stream>>>(
          midb, W2t + (size_t)l * E_ * HID_, b2 + l * E_, hf, xf, nullptr, M_, E_, HID_);
    }
  }
  k_gemm256<<<dim3(8 * 2 * (VPAD_ / 256)), 512, 0, stream>>>(
      xb, Wot, bo, out, VPAD_, E_, VOCAB_, 2);
}

// Round 14
// 1158.937 us; speedup vs baseline: 3.1546x; 1.0230x over previous
//
#include <hip/hip_runtime.h>
#include <stdint.h>

#define DEV static __device__ __forceinline__

typedef unsigned short u16;
typedef __attribute__((ext_vector_type(8))) short short8;
typedef __attribute__((ext_vector_type(4))) float f32x4;

#define B_     2
#define S_     2048
#define E_     768
#define H_     12
#define L_     2
#define HID_   3072
#define VOCAB_ 50257
#define VPAD_  50432
#define M_     4096
#define NQKV_  2304

DEV u16 f2bf(float f) {
  union { float f; unsigned u; } x; x.f = f;
  unsigned r = x.u + 0x7fffu + ((x.u >> 16) & 1u);
  return (u16)(r >> 16);
}

DEV void gload16(const void* g, void* lds) {
  __builtin_amdgcn_global_load_lds(
      (const __attribute__((address_space(1))) unsigned int*)g,
      (__attribute__((address_space(3))) unsigned int*)lds, 16, 0, 0);
}

// ---------------------------------------------------------------- transpose
__global__ __launch_bounds__(256) void k_transp(
    const float* __restrict__ in, u16* __restrict__ out,
    int R, int Cin, long long ib1, long long ib2, long long ob1, long long ob2, int zdiv)
{
  __shared__ float t[32][33];
  const int z = blockIdx.z;
  const float* ib = in  + (size_t)(z / zdiv) * ib1 + (size_t)(z % zdiv) * ib2;
  u16*         ob = out + (size_t)(z / zdiv) * ob1 + (size_t)(z % zdiv) * ob2;
  const int c0 = blockIdx.x * 32, r0 = blockIdx.y * 32;
  const int tx = threadIdx.x, ty = threadIdx.y;
#pragma unroll
  for (int i = 0; i < 4; i++) {
    const int c = c0 + tx, r = r0 + ty + i * 8;
    t[ty + i * 8][tx] = (c < Cin) ? ib[(size_t)r * Cin + c] : 0.f;
  }
  __syncthreads();
#pragma unroll
  for (int i = 0; i < 4; i++) {
    const int orow = c0 + ty + i * 8;
    ob[(size_t)orow * R + r0 + tx] = f2bf(t[tx][ty + i * 8]);
  }
}

__global__ __launch_bounds__(256) void k_pack_bias(
    const float* __restrict__ bq, const float* __restrict__ bk,
    const float* __restrict__ bv, float* __restrict__ bqkv)
{
  const int i = blockIdx.x * 256 + threadIdx.x;
  if (i >= L_ * NQKV_) return;
  const int l = i / NQKV_, n = i % NQKV_;
  const float* s = (n < 768) ? bq : (n < 1536) ? bk : bv;
  bqkv[i] = s[l * 768 + (n % 768)];
}

// ---------------------------------------------------------------- embed + PE
__global__ __launch_bounds__(256) void k_embed(
    const int* __restrict__ tok, const float* __restrict__ emb, float* __restrict__ x)
{
  const int idx = blockIdx.x * 256 + threadIdx.x;
  const int e = idx % E_;
  const int row = idx / E_;
  const int s = row & (S_ - 1);
  const int t = tok[row];
  const float ang = (float)s * expf((float)e * (-2.0f / 768.f) * 9.210340371976184f);
  const float pe = (e & 1) ? cosf(ang) : sinf(ang);
  x[idx] = emb[(size_t)t * E_ + e] + pe;
}

// ---------------------------------------------------------------- layernorm
__global__ __launch_bounds__(256) void k_ln(
    const float* __restrict__ xin, const float* __restrict__ sc,
    const float* __restrict__ bi, float* __restrict__ hout, u16* __restrict__ hb)
{
  const int row  = blockIdx.x * 4 + (threadIdx.x >> 6);
  const int lane = threadIdx.x & 63;
  const float* xr = xin + (size_t)row * E_;
  float v[12];
  float s = 0.f;
#pragma unroll
  for (int i = 0; i < 12; i++) { v[i] = xr[i * 64 + lane]; s += v[i]; }
#pragma unroll
  for (int o = 1; o < 64; o <<= 1) s += __shfl_xor(s, o);
  const float mu = s * (1.f / 768.f);
  float s2 = 0.f;
#pragma unroll
  for (int i = 0; i < 12; i++) { const float d = v[i] - mu; s2 += d * d; }
#pragma unroll
  for (int o = 1; o < 64; o <<= 1) s2 += __shfl_xor(s2, o);
  const float rs = rsqrtf(s2 * (1.f / 768.f) + 1e-5f);
#pragma unroll
  for (int i = 0; i < 12; i++) {
    const int c = i * 64 + lane;
    const float ov = (v[i] - mu) * rs * sc[c] + bi[c];
    hout[(size_t)row * E_ + c] = ov;
    hb[(size_t)row * E_ + c]   = f2bf(ov);
  }
}

// ---------------------------------------------------------------- GEMM (m97 128^2)
// EPI 0: +bias->bf16  1: relu(+bias)->bf16  2: +bias+res->f32  4: EPI2 + bf16 copy
template <int EPI>
__global__ __launch_bounds__(256) void k_gemm(
    const u16* __restrict__ A, const u16* __restrict__ Bt,
    const float* __restrict__ bias, const float* __restrict__ res,
    void* __restrict__ outp, u16* __restrict__ out2, int Mm, int Nn, int Kk)
{
  __shared__ __align__(16) u16 As[128 * 32];
  __shared__ __align__(16) u16 Bs[128 * 32];
  const int tid  = threadIdx.x;
  const int lane = tid & 63;
  const int wid  = tid >> 6;
  const int wr = wid >> 1, wc = wid & 1;
  const int m0 = blockIdx.y * 128, n0 = blockIdx.x * 128;

  const u16* Ab = A  + (size_t)m0 * Kk;
  const u16* Bb = Bt + (size_t)n0 * Kk;

  f32x4 acc[4][4];
#pragma unroll
  for (int i = 0; i < 4; i++)
#pragma unroll
    for (int j = 0; j < 4; j++) acc[i][j] = (f32x4){0.f, 0.f, 0.f, 0.f};

  const int c0 = tid, c1 = 256 + tid;
  const int a0row = c0 >> 2, a0k = (c0 & 3) * 8;
  const int a1row = c1 >> 2, a1k = (c1 & 3) * 8;
  const int nk = Kk >> 5;
  const int kg = (lane >> 4) * 8;
  const int arow = wr * 64 + (lane & 15);
  const int brow = wc * 64 + (lane & 15);

  for (int kt = 0; kt < nk; ++kt) {
    const int kof = kt * 32;
    __syncthreads();
    gload16(Ab + (size_t)a0row * Kk + kof + a0k, &As[c0 * 8]);
    gload16(Ab + (size_t)a1row * Kk + kof + a1k, &As[c1 * 8]);
    gload16(Bb + (size_t)a0row * Kk + kof + a0k, &Bs[c0 * 8]);
    gload16(Bb + (size_t)a1row * Kk + kof + a1k, &Bs[c1 * 8]);
    asm volatile("s_waitcnt vmcnt(0)" ::: "memory");
    __syncthreads();
    short8 af[4], bf[4];
#pragma unroll
    for (int i = 0; i < 4; i++) af[i] = *(const short8*)&As[(arow + i * 16) * 32 + kg];
#pragma unroll
    for (int i = 0; i < 4; i++) bf[i] = *(const short8*)&Bs[(brow + i * 16) * 32 + kg];
#pragma unroll
    for (int mi = 0; mi < 4; mi++)
#pragma unroll
      for (int ni = 0; ni < 4; ni++)
        acc[mi][ni] = __builtin_amdgcn_mfma_f32_16x16x32_bf16(af[mi], bf[ni], acc[mi][ni], 0, 0, 0);
  }

  const int colg = lane & 15;
  const int rowg = (lane >> 4) * 4;
#pragma unroll
  for (int mi = 0; mi < 4; mi++) {
#pragma unroll
    for (int ni = 0; ni < 4; ni++) {
      const int col = n0 + wc * 64 + ni * 16 + colg;
      const float bb = bias[col];
#pragma unroll
      for (int r = 0; r < 4; r++) {
        const int row = m0 + wr * 64 + mi * 16 + rowg + r;
        float v = acc[mi][ni][r] + bb;
        if (EPI == 0)      ((u16*)outp)[(size_t)row * Nn + col] = f2bf(v);
        else if (EPI == 1) ((u16*)outp)[(size_t)row * Nn + col] = f2bf(fmaxf(v, 0.f));
        else if (EPI == 2) ((float*)outp)[(size_t)row * Nn + col] = v + res[(size_t)row * Nn + col];
        else if (EPI == 4) {
          const float o = v + res[(size_t)row * Nn + col];
          ((float*)outp)[(size_t)row * Nn + col] = o;
          out2[(size_t)row * Nn + col] = f2bf(o);
        }
      }
    }
  }
}

// ---------------------------------------------------------------- GEMM thin (64x128 tile) - for MLP2
// N=768 at 128^2 gives only 192 blocks (0.75/CU). 64-row M-tile -> 384 blocks
// (1.5/CU), 12KB LDS -> multiple co-resident blocks. 4 waves, wave w owns
// 64 rows x 32 cols (acc 4x2). Same m97 loop; EPI 2/4 epilogues.
template <int EPI>
__global__ __launch_bounds__(256) void k_gemm_thin(
    const u16* __restrict__ A, const u16* __restrict__ Bt,
    const float* __restrict__ bias, const float* __restrict__ res,
    float* __restrict__ outp, u16* __restrict__ out2, int Nn, int Kk)
{
  __shared__ __align__(16) u16 As[64 * 32];
  __shared__ __align__(16) u16 Bs[128 * 32];
  const int tid  = threadIdx.x;
  const int lane = tid & 63;
  const int wid  = tid >> 6;
  const int m0 = blockIdx.y * 64, n0 = blockIdx.x * 128;

  const u16* Ab = A  + (size_t)m0 * Kk;
  const u16* Bb = Bt + (size_t)n0 * Kk;

  f32x4 acc[4][2];
#pragma unroll
  for (int i = 0; i < 4; i++)
#pragma unroll
    for (int j = 0; j < 2; j++) acc[i][j] = (f32x4){0.f, 0.f, 0.f, 0.f};

  const int c0 = tid, c1 = 256 + tid;
  const int a0row = c0 >> 2, a0k = (c0 & 3) * 8;   // A rows 0..63
  const int a1row = c1 >> 2, a1k = (c1 & 3) * 8;   // B rows 64..127
  const int nk = Kk >> 5;
  const int kg = (lane >> 4) * 8;
  const int l15 = lane & 15;

  for (int kt = 0; kt < nk; ++kt) {
    const int kof = kt * 32;
    __syncthreads();
    gload16(Ab + (size_t)a0row * Kk + kof + a0k, &As[c0 * 8]);
    gload16(Bb + (size_t)a0row * Kk + kof + a0k, &Bs[c0 * 8]);
    gload16(Bb + (size_t)a1row * Kk + kof + a1k, &Bs[c1 * 8]);
    asm volatile("s_waitcnt vmcnt(0)" ::: "memory");
    __syncthreads();
    short8 af[4], bf[2];
#pragma unroll
    for (int i = 0; i < 4; i++) af[i] = *(const short8*)&As[(i * 16 + l15) * 32 + kg];
#pragma unroll
    for (int i = 0; i < 2; i++) bf[i] = *(const short8*)&Bs[(wid * 32 + i * 16 + l15) * 32 + kg];
#pragma unroll
    for (int mi = 0; mi < 4; mi++)
#pragma unroll
      for (int ni = 0; ni < 2; ni++)
        acc[mi][ni] = __builtin_amdgcn_mfma_f32_16x16x32_bf16(af[mi], bf[ni], acc[mi][ni], 0, 0, 0);
  }

  const int colg = lane & 15;
  const int rowg = (lane >> 4) * 4;
#pragma unroll
  for (int mi = 0; mi < 4; mi++) {
#pragma unroll
    for (int ni = 0; ni < 2; ni++) {
      const int col = n0 + wid * 32 + ni * 16 + colg;
      const float bb = bias[col];
#pragma unroll
      for (int r = 0; r < 4; r++) {
        const int row = m0 + mi * 16 + rowg + r;
        const float o = acc[mi][ni][r] + bb + res[(size_t)row * Nn + col];
        outp[(size_t)row * Nn + col] = o;
        if (EPI == 4) out2[(size_t)row * Nn + col] = f2bf(o);
      }
    }
  }
}

// ---------------------------------------------------------------- GEMM 256^2 (vocab) — R7 best (566us)
__global__ __launch_bounds__(512, 2) void k_gemm256(
    const u16* __restrict__ A, const u16* __restrict__ Bt,
    const float* __restrict__ bias, float* __restrict__ out,
    int Nn, int Kk, int nreal, int mpx)
{
  __shared__ __align__(16) u16 As[2][256 * 64];
  __shared__ __align__(16) u16 Bs[2][256 * 64];

  const int id = blockIdx.x;
  const int xcd = id & 7;
  const int j = id >> 3;
  const int m0 = (xcd * mpx + (j % mpx)) * 256;
  const int n0 = (j / mpx) * 256;

  const int tid = threadIdx.x, lane = tid & 63, w = tid >> 6;
  const int wr = w >> 2, wcn = w & 3;
  const int l15 = lane & 15, ks = lane >> 4;

  const u16* Ab = A  + (size_t)m0 * Kk;
  const u16* Bb = Bt + (size_t)n0 * Kk;

  const int srow  = lane >> 3;
  const int sslot = ((lane & 7) ^ srow) * 8;
  const int wrow  = w * 8;

  f32x4 acc[8][4];
#pragma unroll
  for (int i = 0; i < 8; i++)
#pragma unroll
    for (int n = 0; n < 4; n++) acc[i][n] = (f32x4){0.f, 0.f, 0.f, 0.f};

  const int nk = Kk >> 6;

  auto stage = [&](int b, int ko) {
    gload16(Ab + (size_t)(wrow + srow) * Kk + ko + sslot,       &As[b][wrow * 64]);
    gload16(Ab + (size_t)(64 + wrow + srow) * Kk + ko + sslot,  &As[b][(64 + wrow) * 64]);
    gload16(Ab + (size_t)(128 + wrow + srow) * Kk + ko + sslot, &As[b][(128 + wrow) * 64]);
    gload16(Ab + (size_t)(192 + wrow + srow) * Kk + ko + sslot, &As[b][(192 + wrow) * 64]);
    gload16(Bb + (size_t)(wrow + srow) * Kk + ko + sslot,       &Bs[b][wrow * 64]);
    gload16(Bb + (size_t)(64 + wrow + srow) * Kk + ko + sslot,  &Bs[b][(64 + wrow) * 64]);
    gload16(Bb + (size_t)(128 + wrow + srow) * Kk + ko + sslot, &Bs[b][(128 + wrow) * 64]);
    gload16(Bb + (size_t)(192 + wrow + srow) * Kk + ko + sslot, &Bs[b][(192 + wrow) * 64]);
  };

  short8 af[4], bf[4];
  auto ldA = [&](int b, int fmh, int ksub) {
#pragma unroll
    for (int i = 0; i < 4; i++) {
      const int r = wr * 128 + fmh * 64 + i * 16 + l15;
      const int sl = ((ksub * 4 + ks) ^ (r & 7)) * 8;
      af[i] = *(const short8*)&As[b][r * 64 + sl];
    }
  };
  auto ldB = [&](int b, int ksub) {
#pragma unroll
    for (int n = 0; n < 4; n++) {
      const int r = wcn * 64 + n * 16 + l15;
      const int sl = ((ksub * 4 + ks) ^ (r & 7)) * 8;
      bf[n] = *(const short8*)&Bs[b][r * 64 + sl];
    }
  };
  auto mm = [&](int fmh) {
    __builtin_amdgcn_s_setprio(1);
#pragma unroll
    for (int i = 0; i < 4; i++)
#pragma unroll
      for (int n = 0; n < 4; n++)
        acc[fmh * 4 + i][n] =
            __builtin_amdgcn_mfma_f32_16x16x32_bf16(af[i], bf[n], acc[fmh * 4 + i][n], 0, 0, 0);
    __builtin_amdgcn_s_setprio(0);
  };

  stage(0, 0);
  if (nk > 1) {
    stage(1, 64);
    asm volatile("s_waitcnt vmcnt(8)" ::: "memory");
  } else {
    asm volatile("s_waitcnt vmcnt(0)" ::: "memory");
  }
  __builtin_amdgcn_s_barrier();

  for (int t = 0; t < nk; ++t) {
    const int cur = t & 1;
    ldA(cur, 0, 0); ldB(cur, 0); mm(0);
    ldA(cur, 1, 0); mm(1);
    ldA(cur, 0, 1); ldB(cur, 1); mm(0);
    ldA(cur, 1, 1); mm(1);
    __builtin_amdgcn_sched_barrier(0);
    __builtin_amdgcn_s_barrier();
    __builtin_amdgcn_sched_barrier(0);
    if (t + 2 < nk) {
      stage(cur, (t + 2) << 6);
      asm volatile("s_waitcnt vmcnt(8)" ::: "memory");
    } else if (t + 1 < nk) {
      asm volatile("s_waitcnt vmcnt(0)" ::: "memory");
    }
    __builtin_amdgcn_sched_barrier(0);
    __builtin_amdgcn_s_barrier();
    __builtin_amdgcn_sched_barrier(0);
  }

#pragma unroll
  for (int fm = 0; fm < 8; fm++) {
    const int row = m0 + wr * 128 + fm * 16 + ks * 4;
#pragma unroll
    for (int n = 0; n < 4; n++) {
      const int col = n0 + wcn * 64 + n * 16 + l15;
      if (col < nreal) {
        const float bb = bias[col];
#pragma unroll
        for (int r = 0; r < 4; r++)
          out[(size_t)(row + r) * nreal + col] = acc[fm][n][r] + bb;
      }
    }
  }
}

// ---------------------------------------------------------------- attention
// QBLK=128 (8 waves x 16 q-rows), KVBLK=128, reversed launch order.
__global__ __launch_bounds__(512) void k_attn(
    const u16* __restrict__ qkv, const float* __restrict__ h, float* __restrict__ x)
{
  const int tid = threadIdx.x, lane = tid & 63, wid = tid >> 6;
  const int bh = blockIdx.y, b = bh / H_, hh = bh % H_;
  const int q0 = (gridDim.x - 1 - blockIdx.x) * 128;
  const int qw = q0 + wid * 16;

  __shared__ __align__(16) u16 Ks[128 * 72];
  __shared__ __align__(16) u16 Vt[64 * 136];
  __shared__ __align__(16) u16 Ps[8][16 * 136];

  const size_t rowbase = (size_t)b * S_;
  const u16* qb = qkv + rowbase * NQKV_ + hh * 64;
  const u16* kb = qb + 768;
  const u16* vb = qb + 1536;

  const int l15 = lane & 15;
  const int ks  = lane >> 4;
  const int kg  = ks * 8;
  const int ks4 = ks * 4;

  short8 qf0, qf1;
  {
    const u16* g = qb + (size_t)(qw + l15) * NQKV_ + kg;
    qf0 = *(const short8*)g;
    qf1 = *(const short8*)(g + 32);
  }

  f32x4 ov[4];
#pragma unroll
  for (int i = 0; i < 4; i++) ov[i] = (f32x4){0.f, 0.f, 0.f, 0.f};
  float mr[4], lr[4];
#pragma unroll
  for (int r = 0; r < 4; r++) { mr[r] = -1e30f; lr[r] = 0.f; }

  const int srow = tid >> 3;
  const int sc8  = (tid & 7) * 8;
  const int g8   = tid & 7;
  const int nkt  = (q0 >> 7) + 1;

  for (int kt = 0; kt < nkt; ++kt) {
    const int kbase = kt << 7;
    __syncthreads();
#pragma unroll
    for (int pass = 0; pass < 2; ++pass) {
      const int r = srow + pass * 64;
      const size_t gr = (size_t)(kbase + r) * NQKV_;
      const uint4 kd = *(const uint4*)(kb + gr + sc8);
      *(uint4*)&Ks[r * 72 + sc8] = kd;
      const uint4 vd = *(const uint4*)(vb + gr + sc8);
      const u16* ve = (const u16*)&vd;
      const int sb = (((r >> 3) ^ g8) << 3) + (r & 7);
#pragma unroll
      for (int jj = 0; jj < 8; jj++) Vt[(sc8 + jj) * 136 + sb] = ve[jj];
    }
    __syncthreads();

    const bool last = (kt == nkt - 1);
    float p[8][4], mt[4];
#pragma unroll
    for (int r = 0; r < 4; r++) mt[r] = -1e30f;
#pragma unroll
    for (int ct = 0; ct < 8; ++ct) {
      f32x4 s = (f32x4){0.f, 0.f, 0.f, 0.f};
      const short8 kf0 = *(const short8*)&Ks[(ct * 16 + l15) * 72 + kg];
      const short8 kf1 = *(const short8*)&Ks[(ct * 16 + l15) * 72 + 32 + kg];
      s = __builtin_amdgcn_mfma_f32_16x16x32_bf16(qf0, kf0, s, 0, 0, 0);
      s = __builtin_amdgcn_mfma_f32_16x16x32_bf16(qf1, kf1, s, 0, 0, 0);
      const int kc = kbase + ct * 16 + l15;
#pragma unroll
      for (int r = 0; r < 4; r++) {
        float v = s[r] * 0.125f;
        if (last && kc > qw + ks4 + r) v = -1e30f;
        p[ct][r] = v;
        mt[r] = fmaxf(mt[r], v);
      }
    }
#pragma unroll
    for (int r = 0; r < 4; r++) {
#pragma unroll
      for (int off = 1; off < 16; off <<= 1) mt[r] = fmaxf(mt[r], __shfl_xor(mt[r], off));
    }
    float al[4], ps[4];
#pragma unroll
    for (int r = 0; r < 4; r++) {
      const float mn = fmaxf(mr[r], mt[r]);
      al[r] = __expf(mr[r] - mn);
      mr[r] = mn;
      ps[r] = 0.f;
    }
#pragma unroll
    for (int ct = 0; ct < 8; ++ct)
#pragma unroll
      for (int r = 0; r < 4; r++) {
        p[ct][r] = __expf(p[ct][r] - mr[r]);
        ps[r] += p[ct][r];
      }
#pragma unroll
    for (int r = 0; r < 4; r++) {
#pragma unroll
      for (int off = 1; off < 16; off <<= 1) ps[r] += __shfl_xor(ps[r], off);
      lr[r] = lr[r] * al[r] + ps[r];
    }
#pragma unroll
    for (int dt = 0; dt < 4; dt++)
#pragma unroll
      for (int r = 0; r < 4; r++) ov[dt][r] *= al[r];

    u16* pw = &Ps[wid][0];
#pragma unroll
    for (int ct = 0; ct < 8; ++ct)
#pragma unroll
      for (int r = 0; r < 4; r++)
        pw[(ks4 + r) * 136 + ct * 16 + l15] = f2bf(p[ct][r]);
#pragma unroll
    for (int c = 0; c < 4; ++c) {
      const short8 pa = *(const short8*)&pw[l15 * 136 + c * 32 + kg];
#pragma unroll
      for (int dt = 0; dt < 4; dt++) {
        const int d = dt * 16 + l15;
        const int sb = (((c * 4 + ks) ^ ((d >> 3) & 7)) << 3);
        const short8 vf = *(const short8*)&Vt[d * 136 + sb];
        ov[dt] = __builtin_amdgcn_mfma_f32_16x16x32_bf16(pa, vf, ov[dt], 0, 0, 0);
      }
    }
  }

#pragma unroll
  for (int dt = 0; dt < 4; dt++) {
#pragma unroll
    for (int r = 0; r < 4; r++) {
      const int qr = qw + ks4 + r;
      const int col = hh * 64 + dt * 16 + l15;
      const size_t idx = (rowbase + qr) * (size_t)E_ + col;
      x[idx] = h[idx] + ov[dt][r] / lr[r];
    }
  }
}

// ---------------------------------------------------------------- launch
extern "C" void kernel_launch(void* const* d_in, const int* in_sizes, int n_in,
                              void* d_out, int out_size, void* d_ws, size_t ws_size,
                              hipStream_t stream)
{
  const int*   tok  = (const int*)  d_in[0];
  const float* emb  = (const float*)d_in[1];
  const float* ln1s = (const float*)d_in[2];
  const float* ln1b = (const float*)d_in[3];
  const float* Wq   = (const float*)d_in[4];
  const float* bq   = (const float*)d_in[5];
  const float* Wk   = (const float*)d_in[6];
  const float* bk   = (const float*)d_in[7];
  const float* Wv   = (const float*)d_in[8];
  const float* bv   = (const float*)d_in[9];
  const float* ln2s = (const float*)d_in[10];
  const float* ln2b = (const float*)d_in[11];
  const float* W1   = (const float*)d_in[12];
  const float* b1   = (const float*)d_in[13];
  const float* W2   = (const float*)d_in[14];
  const float* b2   = (const float*)d_in[15];
  const float* Wo   = (const float*)d_in[16];
  const float* bo   = (const float*)d_in[17];
  float* out = (float*)d_out;

  char* p = (char*)d_ws;
  float* xf    = (float*)p; p += (size_t)M_ * E_ * 4;
  float* hf    = (float*)p; p += (size_t)M_ * E_ * 4;
  u16*   hb    = (u16*)p;   p += (size_t)M_ * E_ * 2;
  u16*   xb    = (u16*)p;   p += (size_t)M_ * E_ * 2;
  u16*   midb  = (u16*)p;   p += (size_t)M_ * HID_ * 2;
  u16*   qkvb  = (u16*)p;   p += (size_t)M_ * NQKV_ * 2;
  u16*   Wqkvt = (u16*)p;   p += (size_t)L_ * NQKV_ * E_ * 2;
  u16*   W1t   = (u16*)p;   p += (size_t)L_ * HID_ * E_ * 2;
  u16*   W2t   = (u16*)p;   p += (size_t)L_ * E_ * HID_ * 2;
  u16*   Wot   = (u16*)p;   p += (size_t)VPAD_ * E_ * 2;
  float* bqkv  = (float*)p; p += (size_t)L_ * NQKV_ * 4;

  const dim3 tb32(32, 8, 1);
  k_transp<<<dim3(HID_ / 32, E_ / 32, L_), tb32, 0, stream>>>(
      W1, W1t, E_, HID_, (long long)E_ * HID_, 0, (long long)HID_ * E_, 0, 1);
  k_transp<<<dim3(E_ / 32, HID_ / 32, L_), tb32, 0, stream>>>(
      W2, W2t, HID_, E_, (long long)HID_ * E_, 0, (long long)E_ * HID_, 0, 1);
  k_transp<<<dim3(VPAD_ / 32, E_ / 32, 1), tb32, 0, stream>>>(
      Wo, Wot, E_, VOCAB_, 0, 0, 0, 0, 1);
  k_transp<<<dim3(2, E_ / 32, L_ * H_), tb32, 0, stream>>>(
      Wq, Wqkvt, E_, 64, (long long)H_ * E_ * 64, (long long)E_ * 64,
      (long long)NQKV_ * E_, 64LL * E_, H_);
  k_transp<<<dim3(2, E_ / 32, L_ * H_), tb32, 0, stream>>>(
      Wk, Wqkvt + 768 * E_, E_, 64, (long long)H_ * E_ * 64, (long long)E_ * 64,
      (long long)NQKV_ * E_, 64LL * E_, H_);
  k_transp<<<dim3(2, E_ / 32, L_ * H_), tb32, 0, stream>>>(
      Wv, Wqkvt + 1536 * E_, E_, 64, (long long)H_ * E_ * 64, (long long)E_ * 64,
      (long long)NQKV_ * E_, 64LL * E_, H_);
  k_pack_bias<<<18, 256, 0, stream>>>(bq, bk, bv, bqkv);
  k_embed<<<(M_ * E_) / 256, 256, 0, stream>>>(tok, emb, xf);

  for (int l = 0; l < L_; ++l) {
    k_ln<<<M_ / 4, 256, 0, stream>>>(xf, ln1s + l * E_, ln1b + l * E_, hf, hb);
    k_gemm<0><<<dim3(NQKV_ / 128, M_ / 128), 256, 0, stream>>>(
        hb, Wqkvt + (size_t)l * NQKV_ * E_, bqkv + l * NQKV_, nullptr, qkvb, nullptr,
        M_, NQKV_, E_);
    k_attn<<<dim3(S_ / 128, B_ * H_), 512, 0, stream>>>(qkvb, hf, xf);
    k_ln<<<M_ / 4, 256, 0, stream>>>(xf, ln2s + l * E_, ln2b + l * E_, hf, hb);
    k_gemm<1><<<dim3(HID_ / 128, M_ / 128), 256, 0, stream>>>(
        hb, W1t + (size_t)l * HID_ * E_, b1 + l * HID_, nullptr, midb, nullptr,
        M_, HID_, E_);
    if (l == L_ - 1) {
      k_gemm_thin<4><<<dim3(E_ / 128, M_ / 64), 256, 0, stream>>>(
          midb, W2t + (size_t)l * E_ * HID_, b2 + l * E_, hf, xf, xb, E_, HID_);
    } else {
      k_gemm_thin<2><<<dim3(E_ / 128, M_ / 64), 256, 0, stream>>>(
          midb, W2t + (size_t)l * E_ * HID_, b2 + l * E_, hf, xf, nullptr, E_, HID_);
    }
  }
  k_gemm256<<<dim3(8 * 2 * (VPAD_ / 256)), 512, 0, stream>>>(
      xb, Wot, bo, out, VPAD_, E_, VOCAB_, 2);
}